// Round 3
// baseline (902.674 us; speedup 1.0000x reference)
//
#include <hip/hip_runtime.h>
#include <hip/hip_cooperative_groups.h>

namespace cg = cooperative_groups;

#define IMG_H 1024
#define IMG_W 1024
#define NBATCH 8
#define NCH 3
#define NPIX (IMG_H * IMG_W)
#define NTOT (8388608LL)                // 8 * 1024 * 1024

#define BINS1 4096                      // level-1: bits >> 19
#define SH1 19

// fused kernel geometry: 256 blocks x 1024 thr, 32-row bands
#define FB_BLOCKS 256
#define FB_ROWS 32
// fallback geometry
#define SEGS 64
#define ROWS_PER_SEG 16

// ---- workspace layout (bytes) ----
#define WS_MISC_OFF   0                 // lossAcc @0 (8B), gCnt[16] @64, sel1 @128, resid1 @256
#define WS_H1R_OFF    4096
#define WS_H1R_BYTES  (2 * NBATCH * BINS1 * 4)          // 256 KB global u32 hist
#define WS_LOSSP_OFF  (WS_H1R_OFF + WS_H1R_BYTES)       // per-block loss partials
#define WS_LOSSP_BYTES 4096
#define WS_LIST_OFF   (WS_LOSSP_OFF + WS_LOSSP_BYTES)

struct Row3f { float l, c, r; };

__device__ __forceinline__ Row3f load3(const float* __restrict__ img, int y, int x) {
    Row3f o;
    if ((unsigned)y >= (unsigned)IMG_H) { o.l = o.c = o.r = 0.0f; return o; }
    const float* row = img + (size_t)y * IMG_W;
    o.c = row[x];
    o.l = (x > 0)         ? row[x - 1] : 0.0f;
    o.r = (x < IMG_W - 1) ? row[x + 1] : 0.0f;
    return o;
}

// BIT-EXACT vs reference: f32, row-major sequential tap order (verified earlier session).
__device__ __forceinline__ float sobel_g(const Row3f& r0, const Row3f& r1, const Row3f& r2) {
    float gx = r0.r - r0.l;
    gx -= 2.0f * r1.l;
    gx += 2.0f * r1.r;
    gx -= r2.l;
    gx += r2.r;
    float gy = r0.l + 2.0f * r0.c;
    gy += r0.r;
    gy -= r2.l;
    gy -= 2.0f * r2.c;
    gy -= r2.r;
    return fabsf(gx) + fabsf(gy);
}

__device__ __forceinline__ unsigned wave_scan(unsigned s, int lane) {
    #pragma unroll
    for (int off = 1; off < 64; off <<= 1) {
        const unsigned v = __shfl_up(s, off);
        if (lane >= off) s += v;
    }
    return s;
}

// device-scope (agent) L2-bypassing atomics for cross-XCD phase communication
__device__ __forceinline__ void ast_u32(unsigned* p, unsigned v) {
    __hip_atomic_store(p, v, __ATOMIC_RELAXED, __HIP_MEMORY_SCOPE_AGENT);
}
__device__ __forceinline__ unsigned ald_u32(const unsigned* p) {
    return __hip_atomic_load(p, __ATOMIC_RELAXED, __HIP_MEMORY_SCOPE_AGENT);
}
__device__ __forceinline__ void ast_u64(unsigned long long* p, unsigned long long v) {
    __hip_atomic_store(p, v, __ATOMIC_RELAXED, __HIP_MEMORY_SCOPE_AGENT);
}
__device__ __forceinline__ unsigned long long ald_u64(const unsigned long long* p) {
    return __hip_atomic_load(p, __ATOMIC_RELAXED, __HIP_MEMORY_SCOPE_AGENT);
}
__device__ __forceinline__ unsigned long long pack64(unsigned bits, unsigned idx) {
    return (unsigned long long)bits | ((unsigned long long)idx << 32);
}

// ================= fused cooperative kernel: zero -> stencil+hist -> select1 -> masks -> selectfix
extern "C" __global__ __launch_bounds__(1024, 4)
void k_fused(const float* __restrict__ A, const float* __restrict__ B,
             const float* __restrict__ F, const int* __restrict__ kptr,
             float* __restrict__ out,
             unsigned* __restrict__ hist1r, unsigned long long* __restrict__ lossPart,
             unsigned* __restrict__ gCnt, unsigned* __restrict__ sel1,
             unsigned* __restrict__ resid1, unsigned long long* __restrict__ list,
             unsigned cap)
{
    cg::grid_group grid = cg::this_grid();

    __shared__ unsigned h[4 * BINS1];               // 64 KB: phase1 hist (2 copies), reused later
    __shared__ double lsum[16];
    __shared__ double dsum[16];
    __shared__ unsigned wsum[16];
    __shared__ unsigned bcast[4];
    __shared__ unsigned cntA, cntB, baseA, baseB;

    const int blk = blockIdx.x;
    const int t = threadIdx.x;
    const int lane = t & 63, wid = t >> 6;
    const int batch = blk >> 5;
    const int y0 = (blk & 31) * FB_ROWS;
    const int x = t;

    // ---------- phase 0: zero hist + counters (replaces host memset) ----------
    {
        const int idx = blk * 1024 + t;
        if (idx < 2 * NBATCH * BINS1) ast_u32(&hist1r[idx], 0u);
        if (blk == 0 && t < 16) ast_u32(&gCnt[t], 0u);
    }
    __threadfence();
    grid.sync();

    // ---------- phase 1: stencil + LDS hist + loss; keep grad bits in registers ----------
    for (int i = t; i < 4 * BINS1; i += 1024) h[i] = 0u;
    __syncthreads();

    unsigned* hc = h + (t >> 9) * (2 * BINS1);      // half-block replicated copy

    const float* a = A + (size_t)batch * NCH * NPIX;
    const float* b = B + (size_t)batch * NCH * NPIX;
    const float* f = F + (size_t)batch * NCH * NPIX;

    unsigned uAr[FB_ROWS], uBr[FB_ROWS];            // statically-indexed (full unroll) -> VGPRs

    {
        Row3f a0 = load3(a, y0 - 1, x), a1 = load3(a, y0, x), a2;
        Row3f b0 = load3(b, y0 - 1, x), b1 = load3(b, y0, x), b2;
        Row3f f0 = load3(f, y0 - 1, x), f1 = load3(f, y0, x), f2;
        double loss = 0.0;
        #pragma unroll
        for (int i = 0; i < FB_ROWS; ++i) {
            const int y = y0 + i;
            a2 = load3(a, y + 1, x);
            b2 = load3(b, y + 1, x);
            f2 = load3(f, y + 1, x);
            const float gA = sobel_g(a0, a1, a2);
            const float gB = sobel_g(b0, b1, b2);
            const float gF = sobel_g(f0, f1, f2);
            const unsigned uA = __float_as_uint(gA), uB = __float_as_uint(gB);
            uAr[i] = uA; uBr[i] = uB;
            atomicAdd(&hc[uA >> SH1], 1u);
            atomicAdd(&hc[BINS1 + (uB >> SH1)], 1u);
            loss += (double)fabsf(gF - fmaxf(gA, gB));
            a0 = a1; a1 = a2;
            b0 = b1; b1 = b2;
            f0 = f1; f1 = f2;
        }
        __syncthreads();

        // merge both LDS copies into global hist (skip zero bins)
        for (int i = t; i < 2 * BINS1; i += 1024) {
            const unsigned v = h[i] + h[2 * BINS1 + i];
            if (v) {
                unsigned* dst = (i < BINS1)
                    ? &hist1r[(size_t)batch * BINS1 + i]
                    : &hist1r[(size_t)(NBATCH + batch) * BINS1 + (i - BINS1)];
                atomicAdd(dst, v);
            }
        }

        for (int off = 32; off > 0; off >>= 1) loss += __shfl_down(loss, off);
        if (lane == 0) lsum[wid] = loss;
        __syncthreads();
        if (t == 0) {
            double s = 0.0;
            for (int i = 0; i < 16; ++i) s += lsum[i];
            ast_u64(&lossPart[blk], (unsigned long long)__double_as_longlong(s));
        }
    }
    __threadfence();
    grid.sync();

    // ---------- phase 2: rank-select level-1 bin (blocks 0..15); loss total (block 0) ----------
    double lossTotal = 0.0;                         // meaningful only on blk 0, t 0
    if (blk < 16) {
        const int ib = blk;
        long long kl = (long long)kptr[0];
        if (kl < 1 || kl > (long long)NPIX) {       // defensive: scalar sent as f32?
            float kf = ((const float*)kptr)[0];
            kl = (long long)kf;
            if (kl < 1) kl = 1;
            if (kl > NPIX) kl = NPIX;
        }
        const unsigned k = (unsigned)kl;

        const unsigned* hr = hist1r + (size_t)ib * BINS1 + 4 * t;
        const unsigned c0 = ald_u32(hr + 0), c1 = ald_u32(hr + 1);
        const unsigned c2 = ald_u32(hr + 2), c3 = ald_u32(hr + 3);
        const unsigned s = c0 + c1 + c2 + c3;

        unsigned incl = wave_scan(s, lane);
        if (lane == 63) wsum[wid] = incl;
        __syncthreads();
        if (wid == 0) {
            unsigned w = (lane < 16) ? wsum[lane] : 0u;
            w = wave_scan(w, lane);
            if (lane < 16) wsum[lane] = w;
        }
        __syncthreads();
        if (wid > 0) incl += wsum[wid - 1];

        const unsigned excl = incl - s;
        if (excl < k && k <= incl) {                // unique winner thread
            unsigned cum = excl; unsigned bin = (unsigned)t * 4u;
            if (cum + c0 < k) { cum += c0; ++bin;
              if (cum + c1 < k) { cum += c1; ++bin;
                if (cum + c2 < k) { cum += c2; ++bin; } } }
            ast_u32(&sel1[ib], bin);
            ast_u32(&resid1[ib], k - cum);
        }
    }
    if (blk == 0) {
        double v = 0.0;
        if (t < FB_BLOCKS) v = __longlong_as_double((long long)ald_u64(&lossPart[t]));
        for (int off = 32; off > 0; off >>= 1) v += __shfl_down(v, off);
        if (lane == 0) dsum[wid] = v;
        __syncthreads();
        if (t == 0) {
            double s = 0.0;
            for (int i = 0; i < 16; ++i) s += dsum[i];
            lossTotal = s;
        }
    }
    __threadfence();
    grid.sync();

    // ---------- phase 3: masks + boundary candidate lists from REGISTER grads ----------
    {
        const unsigned sA = ald_u32(&sel1[batch]);
        const unsigned sB = ald_u32(&sel1[NBATCH + batch]);
        float* mA = out + 1 + (size_t)batch * NPIX;
        float* mB = out + 1 + (size_t)NTOT + (size_t)batch * NPIX;
        unsigned long long* LA = list + (size_t)batch * cap;
        unsigned long long* LB = list + (size_t)(NBATCH + batch) * cap;
        unsigned long long* bufA = (unsigned long long*)h;          // 16 KB
        unsigned long long* bufB = ((unsigned long long*)h) + 2048; // 16 KB

        if (t == 0) { cntA = 0u; cntB = 0u; }
        __syncthreads();

        #pragma unroll
        for (int i = 0; i < FB_ROWS; ++i) {
            const unsigned uA = uAr[i], uB = uBr[i];
            const unsigned binA = uA >> SH1, binB = uB >> SH1;
            const unsigned idx = (unsigned)(y0 + i) * IMG_W + (unsigned)x;
            mA[idx] = (binA > sA) ? 1.0f : 0.0f;    // boundary bin: provisional 0, fixed in phase 4
            mB[idx] = (binB > sB) ? 1.0f : 0.0f;
            if (binA == sA) { unsigned p = atomicAdd(&cntA, 1u); bufA[p] = pack64(uA, idx); }
            if (binB == sB) { unsigned p = atomicAdd(&cntB, 1u); bufB[p] = pack64(uB, idx); }

            __syncthreads();                        // appends visible, counters stable
            const bool last = (i == FB_ROWS - 1);
            const unsigned nA = cntA, nB = cntB;    // uniform
            const bool doA = (nA >= 1024u) || (last && nA > 0u);
            const bool doB = (nB >= 1024u) || (last && nB > 0u);
            if (doA || doB) {
                if (t == 0) {
                    if (doA) baseA = atomicAdd(&gCnt[batch], nA);
                    if (doB) baseB = atomicAdd(&gCnt[NBATCH + batch], nB);
                }
                __syncthreads();
                if (doA) {
                    const unsigned bs = baseA;
                    for (unsigned j = t; j < nA; j += 1024u) {
                        const unsigned d = bs + j;
                        if (d < cap) ast_u64(&LA[d], bufA[j]);
                    }
                }
                if (doB) {
                    const unsigned bs = baseB;
                    for (unsigned j = t; j < nB; j += 1024u) {
                        const unsigned d = bs + j;
                        if (d < cap) ast_u64(&LB[d], bufB[j]);
                    }
                }
                __syncthreads();
                if (t == 0) { if (doA) cntA = 0u; if (doB) cntB = 0u; }
            }
            __syncthreads();
        }
    }
    __threadfence();                                // write back dirty mask lines before fixup phase
    grid.sync();
    __threadfence();

    // ---------- phase 4: 19-bit select within boundary bin + mask fix-up (blocks 0..15) ----------
    if (blk < 16) {
        const int ib = blk;
        unsigned n = ald_u32(&gCnt[ib]); if (n > cap) n = cap;
        const unsigned kk = ald_u32(&resid1[ib]);
        const unsigned long long* L = list + (size_t)ib * cap;
        unsigned* h2 = h;                           // reuse 16 KB of the big LDS block

        if (t < 4) bcast[t] = 0u;
        for (int i = t; i < BINS1; i += 1024) h2[i] = 0u;
        __syncthreads();

        // level-2: hist of (bits>>7)&4095
        for (unsigned j = t; j < n; j += 1024u) {
            const unsigned bits = (unsigned)ald_u64(&L[j]);
            atomicAdd(&h2[(bits >> 7) & 4095u], 1u);
        }
        __syncthreads();

        const unsigned c0 = h2[4 * t], c1 = h2[4 * t + 1], c2 = h2[4 * t + 2], c3 = h2[4 * t + 3];
        const unsigned s = c0 + c1 + c2 + c3;
        unsigned incl = wave_scan(s, lane);
        if (lane == 63) wsum[wid] = incl;
        __syncthreads();
        if (wid == 0) {
            unsigned w = (lane < 16) ? wsum[lane] : 0u;
            w = wave_scan(w, lane);
            if (lane < 16) wsum[lane] = w;
        }
        __syncthreads();
        if (wid > 0) incl += wsum[wid - 1];
        {
            const unsigned excl = incl - s;
            if (excl < kk && kk <= incl) {
                unsigned cum = excl; unsigned bin = 4u * (unsigned)t;
                if (cum + c0 < kk) { cum += c0; ++bin;
                  if (cum + c1 < kk) { cum += c1; ++bin;
                    if (cum + c2 < kk) { cum += c2; ++bin; } } }
                bcast[0] = bin;
                bcast[1] = kk - cum;
            }
        }
        __syncthreads();
        const unsigned sel2 = bcast[0], k3 = bcast[1];

        // level-3: hist of bits&127 among entries matching sel2
        if (t < 128) h2[t] = 0u;
        __syncthreads();
        for (unsigned j = t; j < n; j += 1024u) {
            const unsigned bits = (unsigned)ald_u64(&L[j]);
            if (((bits >> 7) & 4095u) == sel2) atomicAdd(&h2[bits & 127u], 1u);
        }
        __syncthreads();
        {
            const unsigned s3 = (t < 128) ? h2[t] : 0u;
            unsigned incl3 = wave_scan(s3, lane);
            if (lane == 63) wsum[wid] = incl3;
            __syncthreads();
            if (wid == 0) {
                unsigned w = (lane < 16) ? wsum[lane] : 0u;
                w = wave_scan(w, lane);
                if (lane < 16) wsum[lane] = w;
            }
            __syncthreads();
            if (wid > 0) incl3 += wsum[wid - 1];
            const unsigned excl3 = incl3 - s3;
            if (t < 128 && excl3 < k3 && k3 <= incl3) {
                bcast[2] = (ald_u32(&sel1[ib]) << SH1) | (sel2 << 7) | (unsigned)t;
            }
        }
        __syncthreads();
        const unsigned kth = bcast[2];

        float* m = out + 1 + (size_t)ib * NPIX;     // [A(0..7) | B(8..15)] contiguous
        for (unsigned j = t; j < n; j += 1024u) {
            const unsigned long long e = ald_u64(&L[j]);
            m[(unsigned)(e >> 32)] = ((unsigned)e >= kth) ? 1.0f : 0.0f;
        }
        if (ib == 0 && t == 0) out[0] = (float)(lossTotal * (1.0 / 8388608.0));
    }
}

// ======================= fallback path: round-2 separate kernels (known good) =======================
extern "C" __global__ __launch_bounds__(1024)
void k_pass0(const float* __restrict__ A, const float* __restrict__ B,
             const float* __restrict__ F,
             unsigned int* __restrict__ hist1r, double* __restrict__ lossPart)
{
    __shared__ unsigned int h[4 * BINS1];
    __shared__ double lsum[16];
    const int t = threadIdx.x;
    const int lane = t & 63;
    for (int i = t; i < 4 * BINS1; i += 1024) h[i] = 0u;
    __syncthreads();

    const int blk = blockIdx.x;
    const int batch = blk >> 6;
    const int y0 = (blk & 63) * ROWS_PER_SEG;
    const int x = t;
    unsigned int* hc = h + (t >> 9) * (2 * BINS1);

    const float* a = A + (size_t)batch * NCH * NPIX;
    const float* b = B + (size_t)batch * NCH * NPIX;
    const float* f = F + (size_t)batch * NCH * NPIX;

    Row3f a0 = load3(a, y0 - 1, x), a1 = load3(a, y0, x), a2;
    Row3f b0 = load3(b, y0 - 1, x), b1 = load3(b, y0, x), b2;
    Row3f f0 = load3(f, y0 - 1, x), f1 = load3(f, y0, x), f2;

    double loss = 0.0;
    for (int i = 0; i < ROWS_PER_SEG; ++i) {
        const int y = y0 + i;
        a2 = load3(a, y + 1, x);
        b2 = load3(b, y + 1, x);
        f2 = load3(f, y + 1, x);
        const float gA = sobel_g(a0, a1, a2);
        const float gB = sobel_g(b0, b1, b2);
        const float gF = sobel_g(f0, f1, f2);
        atomicAdd(&hc[__float_as_uint(gA) >> SH1], 1u);
        atomicAdd(&hc[BINS1 + (__float_as_uint(gB) >> SH1)], 1u);
        loss += (double)fabsf(gF - fmaxf(gA, gB));
        a0 = a1; a1 = a2;
        b0 = b1; b1 = b2;
        f0 = f1; f1 = f2;
    }
    __syncthreads();

    for (int i = t; i < 2 * BINS1; i += 1024) {
        const unsigned v = h[i] + h[2 * BINS1 + i];
        if (v) {
            unsigned int* dst = (i < BINS1)
                ? &hist1r[(size_t)batch * BINS1 + i]
                : &hist1r[(size_t)(NBATCH + batch) * BINS1 + (i - BINS1)];
            atomicAdd(dst, v);
        }
    }

    for (int off = 32; off > 0; off >>= 1) loss += __shfl_down(loss, off);
    if (lane == 0) lsum[t >> 6] = loss;
    __syncthreads();
    if (t == 0) {
        double s = 0.0;
        for (int i = 0; i < 16; ++i) s += lsum[i];
        lossPart[blk] = s;
    }
}

extern "C" __global__ __launch_bounds__(1024)
void k_select1(const unsigned int* __restrict__ hist1r, const double* __restrict__ lossPart,
               const int* __restrict__ kptr, int* __restrict__ sel1, int* __restrict__ resid1,
               double* __restrict__ lossAcc, unsigned int* __restrict__ gCnt)
{
    const int ib = blockIdx.x, t = threadIdx.x;
    const int lane = t & 63, wid = t >> 6;

    long long kl = (long long)kptr[0];
    if (kl < 1 || kl > (long long)NPIX) {
        float kf = ((const float*)kptr)[0];
        kl = (long long)kf;
        if (kl < 1) kl = 1;
        if (kl > NPIX) kl = NPIX;
    }
    const unsigned k = (unsigned)kl;

    const uint4 c = ((const uint4*)(hist1r + (size_t)ib * BINS1))[t];
    const unsigned s = c.x + c.y + c.z + c.w;

    unsigned incl = wave_scan(s, lane);
    __shared__ unsigned wsum[16];
    __shared__ double dsum[16];
    if (lane == 63) wsum[wid] = incl;
    __syncthreads();
    if (wid == 0) {
        unsigned w = (lane < 16) ? wsum[lane] : 0u;
        w = wave_scan(w, lane);
        if (lane < 16) wsum[lane] = w;
    }
    __syncthreads();
    if (wid > 0) incl += wsum[wid - 1];

    const unsigned excl = incl - s;
    if (excl < k && k <= incl) {
        unsigned cum = excl; int bin = t * 4;
        if (cum + c.x < k) { cum += c.x; ++bin;
          if (cum + c.y < k) { cum += c.y; ++bin;
            if (cum + c.z < k) { cum += c.z; ++bin; } } }
        sel1[ib] = bin;
        resid1[ib] = (int)(k - cum);
    }

    double v = 0.0;
    if (ib == 0 && t < NBATCH * SEGS) v = lossPart[t];
    for (int off = 32; off > 0; off >>= 1) v += __shfl_down(v, off);
    if (lane == 0) dsum[wid] = v;
    __syncthreads();
    if (ib == 0 && t == 0) {
        double sL = 0.0;
        for (int i = 0; i < 16; ++i) sL += dsum[i];
        lossAcc[0] = sL;
    }
    if (t == 0) gCnt[ib] = 0u;
}

extern "C" __global__ __launch_bounds__(1024)
void k_passB(const float* __restrict__ A, const float* __restrict__ B,
             const int* __restrict__ sel1, unsigned int* __restrict__ gCnt,
             uint2* __restrict__ list, unsigned cap, float* __restrict__ out)
{
    const int t = threadIdx.x;
    const int blk = blockIdx.x;
    const int batch = blk >> 6;
    const int y0 = (blk & 63) * ROWS_PER_SEG;
    const int x = t;

    const float* a = A + (size_t)batch * NCH * NPIX;
    const float* b = B + (size_t)batch * NCH * NPIX;
    const unsigned sA = (unsigned)sel1[batch];
    const unsigned sB = (unsigned)sel1[NBATCH + batch];
    float* mA = out + 1 + (size_t)batch * NPIX;
    float* mB = out + 1 + (size_t)NTOT + (size_t)batch * NPIX;

    __shared__ uint2 bufA[2048], bufB[2048];
    __shared__ unsigned cntA, cntB, baseA, baseB;
    if (t == 0) { cntA = 0u; cntB = 0u; }
    __syncthreads();

    Row3f a0 = load3(a, y0 - 1, x), a1 = load3(a, y0, x), a2;
    Row3f b0 = load3(b, y0 - 1, x), b1 = load3(b, y0, x), b2;
    for (int i = 0; i < ROWS_PER_SEG; ++i) {
        const int y = y0 + i;
        a2 = load3(a, y + 1, x);
        b2 = load3(b, y + 1, x);
        const unsigned uA = __float_as_uint(sobel_g(a0, a1, a2));
        const unsigned uB = __float_as_uint(sobel_g(b0, b1, b2));
        const unsigned binA = uA >> SH1, binB = uB >> SH1;
        const unsigned idx = (unsigned)y * IMG_W + (unsigned)x;
        mA[idx] = (binA > sA) ? 1.0f : 0.0f;
        mB[idx] = (binB > sB) ? 1.0f : 0.0f;
        if (binA == sA) { unsigned p = atomicAdd(&cntA, 1u); bufA[p] = make_uint2(uA, idx); }
        if (binB == sB) { unsigned p = atomicAdd(&cntB, 1u); bufB[p] = make_uint2(uB, idx); }
        a0 = a1; a1 = a2;
        b0 = b1; b1 = b2;

        __syncthreads();
        const bool last = (i == ROWS_PER_SEG - 1);
        const unsigned nA = cntA, nB = cntB;
        const bool doA = (nA >= 1024u) || (last && nA > 0u);
        const bool doB = (nB >= 1024u) || (last && nB > 0u);
        if (doA || doB) {
            if (t == 0) {
                if (doA) baseA = atomicAdd(&gCnt[batch], nA);
                if (doB) baseB = atomicAdd(&gCnt[NBATCH + batch], nB);
            }
            __syncthreads();
            if (doA) {
                const unsigned bs = baseA;
                for (unsigned j = t; j < nA; j += 1024u) {
                    const unsigned d = bs + j;
                    if (d < cap) list[(size_t)batch * cap + d] = bufA[j];
                }
            }
            if (doB) {
                const unsigned bs = baseB;
                for (unsigned j = t; j < nB; j += 1024u) {
                    const unsigned d = bs + j;
                    if (d < cap) list[(size_t)(NBATCH + batch) * cap + d] = bufB[j];
                }
            }
            __syncthreads();
            if (t == 0) { if (doA) cntA = 0u; if (doB) cntB = 0u; }
        }
        __syncthreads();
    }
}

extern "C" __global__ __launch_bounds__(1024)
void k_selectfix(const uint2* __restrict__ list, const unsigned int* __restrict__ gCnt,
                 unsigned cap, const int* __restrict__ sel1, const int* __restrict__ resid1,
                 const double* __restrict__ lossAcc, float* __restrict__ out)
{
    const int ib = blockIdx.x, t = threadIdx.x;
    const int lane = t & 63, wid = t >> 6;
    unsigned n = gCnt[ib]; if (n > cap) n = cap;
    const unsigned kk = (unsigned)resid1[ib];
    const uint2* L = list + (size_t)ib * cap;

    __shared__ unsigned h2[BINS1];
    __shared__ unsigned wsum[16];
    __shared__ unsigned bcast[4];
    if (t < 4) bcast[t] = 0u;
    for (int i = t; i < BINS1; i += 1024) h2[i] = 0u;
    __syncthreads();

    for (unsigned j = t; j < n; j += 1024u) atomicAdd(&h2[(L[j].x >> 7) & 4095u], 1u);
    __syncthreads();

    const unsigned c0 = h2[4 * t], c1 = h2[4 * t + 1], c2 = h2[4 * t + 2], c3 = h2[4 * t + 3];
    const unsigned s = c0 + c1 + c2 + c3;
    unsigned incl = wave_scan(s, lane);
    if (lane == 63) wsum[wid] = incl;
    __syncthreads();
    if (wid == 0) {
        unsigned w = (lane < 16) ? wsum[lane] : 0u;
        w = wave_scan(w, lane);
        if (lane < 16) wsum[lane] = w;
    }
    __syncthreads();
    if (wid > 0) incl += wsum[wid - 1];
    {
        const unsigned excl = incl - s;
        if (excl < kk && kk <= incl) {
            unsigned cum = excl; unsigned bin = 4u * t;
            if (cum + c0 < kk) { cum += c0; ++bin;
              if (cum + c1 < kk) { cum += c1; ++bin;
                if (cum + c2 < kk) { cum += c2; ++bin; } } }
            bcast[0] = bin;
            bcast[1] = kk - cum;
        }
    }
    __syncthreads();
    const unsigned sel2 = bcast[0], k3 = bcast[1];

    if (t < 128) h2[t] = 0u;
    __syncthreads();
    for (unsigned j = t; j < n; j += 1024u) {
        const unsigned bbits = L[j].x;
        if (((bbits >> 7) & 4095u) == sel2) atomicAdd(&h2[bbits & 127u], 1u);
    }
    __syncthreads();
    {
        const unsigned s3 = (t < 128) ? h2[t] : 0u;
        unsigned incl3 = wave_scan(s3, lane);
        if (lane == 63) wsum[wid] = incl3;
        __syncthreads();
        if (wid == 0) {
            unsigned w = (lane < 16) ? wsum[lane] : 0u;
            w = wave_scan(w, lane);
            if (lane < 16) wsum[lane] = w;
        }
        __syncthreads();
        if (wid > 0) incl3 += wsum[wid - 1];
        const unsigned excl3 = incl3 - s3;
        if (t < 128 && excl3 < k3 && k3 <= incl3) {
            bcast[2] = ((unsigned)sel1[ib] << SH1) | (sel2 << 7) | (unsigned)t;
        }
    }
    __syncthreads();
    const unsigned kth = bcast[2];

    float* m = out + 1 + (size_t)ib * NPIX;
    for (unsigned j = t; j < n; j += 1024u) {
        const uint2 e = L[j];
        m[e.y] = (e.x >= kth) ? 1.0f : 0.0f;
    }
    if (ib == 0 && t == 0) out[0] = (float)(lossAcc[0] * (1.0 / 8388608.0));
}

extern "C" void kernel_launch(void* const* d_in, const int* in_sizes, int n_in,
                              void* d_out, int out_size, void* d_ws, size_t ws_size,
                              hipStream_t stream)
{
    const float* A = (const float*)d_in[0];
    const float* B = (const float*)d_in[1];
    const float* F = (const float*)d_in[2];
    const int* kptr = (const int*)d_in[3];
    float* out = (float*)d_out;

    if (ws_size < (size_t)WS_LIST_OFF + 16 * 8 * 1024) return;

    char* ws = (char*)d_ws;
    double* lossAcc        = (double*)(ws + WS_MISC_OFF);
    unsigned int* gCnt     = (unsigned int*)(ws + WS_MISC_OFF + 64);
    int* sel1              = (int*)(ws + WS_MISC_OFF + 128);
    int* resid1            = (int*)(ws + WS_MISC_OFF + 256);
    unsigned int* hist1r   = (unsigned int*)(ws + WS_H1R_OFF);
    double* lossPart       = (double*)(ws + WS_LOSSP_OFF);
    uint2* list            = (uint2*)(ws + WS_LIST_OFF);

    unsigned long long capll = (ws_size - WS_LIST_OFF) / (16ull * 8ull);
    unsigned cap = (capll > (unsigned long long)NPIX) ? (unsigned)NPIX : (unsigned)capll;

    // ---- primary: single cooperative dispatch (does its own zeroing) ----
    {
        unsigned* sel1u = (unsigned*)sel1;
        unsigned* resid1u = (unsigned*)resid1;
        unsigned long long* lossPart64 = (unsigned long long*)lossPart;
        unsigned long long* list64 = (unsigned long long*)list;
        void* kargs[] = {
            (void*)&A, (void*)&B, (void*)&F, (void*)&kptr, (void*)&out,
            (void*)&hist1r, (void*)&lossPart64, (void*)&gCnt,
            (void*)&sel1u, (void*)&resid1u, (void*)&list64, (void*)&cap
        };
        hipError_t e = hipLaunchCooperativeKernel((const void*)k_fused,
                                                  dim3(FB_BLOCKS), dim3(1024),
                                                  kargs, 0, stream);
        if (e == hipSuccess) return;
    }

    // ---- fallback: round-2 four-kernel path ----
    hipMemsetAsync(ws + WS_H1R_OFF, 0, WS_H1R_BYTES, stream);
    k_pass0    <<<dim3(NBATCH * SEGS), dim3(1024), 0, stream>>>(A, B, F, hist1r, lossPart);
    k_select1  <<<dim3(2 * NBATCH), dim3(1024), 0, stream>>>(hist1r, lossPart, kptr, sel1, resid1, lossAcc, gCnt);
    k_passB    <<<dim3(NBATCH * SEGS), dim3(1024), 0, stream>>>(A, B, sel1, gCnt, list, cap, out);
    k_selectfix<<<dim3(2 * NBATCH), dim3(1024), 0, stream>>>(list, gCnt, cap, sel1, resid1, lossAcc, out);
}